// Round 1
// baseline (626.461 us; speedup 1.0000x reference)
//
#include <hip/hip_runtime.h>
#include <math.h>

#define Bn 16
#define Cn 64
#define Tn 1024
#define Dn 1024

// ---- workspace layout (float element offsets) ----
#define CA_S   1088                             // ca row: 32 zero | 1024 data | 32 zero
#define CA_OFF 0
#define A1_S   1072                             // a1 row: 16 zero | 1025 data | 31 zero
#define A1_OFF (CA_OFF + Bn*CA_S)
#define A2_S   1026                             // a2 row: 1026 data
#define A2_OFF (A1_OFF + Bn*32*A1_S)
#define AT_OFF (A2_OFF + Bn*64*A2_S)            // attn [B][1024]
#define HS_S   1040                             // unpooled Hsum row: 1025 data
#define HS_OFF (AT_OFF + Bn*1024)               // [4][B][64][HS_S]
#define HB_OFF (HS_OFF + 4*Bn*64*HS_S)          // hbar [B][64][1024]

// K0: zero the padding regions of ca and a1 (ws is poisoned 0xAA every launch)
__global__ void k0_zero(float* ws) {
  int id = blockIdx.x * 256 + threadIdx.x;
  if (id < Bn * 64) {
    int b = id >> 6, j = id & 63;
    int pos = (j < 32) ? j : (1056 + j - 32);
    ws[CA_OFF + b * CA_S + pos] = 0.f;
  }
  int id2 = id - Bn * 64;
  if (id2 >= 0 && id2 < Bn * 32 * 47) {
    int row = id2 / 47, j = id2 % 47;
    int pos = (j < 16) ? j : (1041 + j - 16);
    ws[A1_OFF + row * A1_S + pos] = 0.f;
  }
}

// K1: ca[b,t] = fs * mean_c eeg[b,c,t]
__global__ void k1_ca(const float* __restrict__ eeg, const float* __restrict__ fsp,
                      float* __restrict__ ws) {
  int b = blockIdx.y, t = blockIdx.x * 256 + threadIdx.x;
  float s = 0.f;
#pragma unroll 8
  for (int c = 0; c < 64; ++c) s += eeg[(b * 64 + c) * 1024 + t];
  ws[CA_OFF + b * CA_S + 32 + t] = s * fsp[0] * (1.f / 64.f);
}

// K2: a1 = relu(conv1d(ca, aw1[32,1,64], pad=32)), len 1025
__global__ void k2_conv1(const float* __restrict__ aw1, const float* __restrict__ ab1,
                         float* __restrict__ ws) {
  int t = blockIdx.x * 256 + threadIdx.x;
  int o = blockIdx.y, b = blockIdx.z;
  if (t >= 1025) return;
  const float* cab = ws + CA_OFF + b * CA_S;
  float acc = ab1[o];
#pragma unroll 8
  for (int k = 0; k < 64; ++k) acc += aw1[o * 64 + k] * cab[t + k];
  ws[A1_OFF + (b * 32 + o) * A1_S + 16 + t] = fmaxf(acc, 0.f);
}

// K3: a2 = relu(conv1d(a1, aw2[64,32,32], pad=16)), len 1026
// block(64,4): 64 t-positions x 4 o-groups of 8; grid(17, B, 2 o-halves)
__global__ __launch_bounds__(256) void k3_conv2(const float* __restrict__ aw2,
                                                const float* __restrict__ ab2,
                                                float* __restrict__ ws) {
  int tx = threadIdx.x, ty = threadIdx.y;
  int t0 = blockIdx.x * 64, b = blockIdx.y, oh = blockIdx.z;
  __shared__ float xl[32 * 96];
  int tid = ty * 64 + tx;
  for (int r = 0; r < 12; ++r) {
    int e = tid + 256 * r;
    if (e < 32 * 95) {
      int i = e / 95, j = e % 95;
      int idx = t0 + j;
      xl[i * 96 + j] = (idx < A1_S) ? ws[A1_OFF + (b * 32 + i) * A1_S + idx] : 0.f;
    }
  }
  __syncthreads();
  int obase = oh * 32 + ty * 8;
  float acc[8];
#pragma unroll
  for (int oo = 0; oo < 8; ++oo) acc[oo] = ab2[obase + oo];
  for (int i = 0; i < 32; ++i) {
#pragma unroll
    for (int k4 = 0; k4 < 8; ++k4) {
      float4 w4[8];
#pragma unroll
      for (int oo = 0; oo < 8; ++oo)
        w4[oo] = *(const float4*)&aw2[((obase + oo) * 32 + i) * 32 + k4 * 4];
      float xv[4];
#pragma unroll
      for (int j = 0; j < 4; ++j) xv[j] = xl[i * 96 + tx + k4 * 4 + j];
#pragma unroll
      for (int oo = 0; oo < 8; ++oo)
        acc[oo] += w4[oo].x * xv[0] + w4[oo].y * xv[1] + w4[oo].z * xv[2] + w4[oo].w * xv[3];
    }
  }
  int t2 = t0 + tx;
  if (t2 < 1026) {
#pragma unroll
    for (int oo = 0; oo < 8; ++oo)
      ws[A2_OFF + (b * 64 + obase + oo) * A2_S + t2] = fmaxf(acc[oo], 0.f);
  }
}

// K4: adaptive pool 1026->1024 (bins of 2, +1 offset past i=512) + 1x1 conv + sigmoid
__global__ void k4_attn(const float* __restrict__ aw3, const float* __restrict__ ab3,
                        float* __restrict__ ws, float* __restrict__ out) {
  int b = blockIdx.y, t = blockIdx.x * 256 + threadIdx.x;
  int s = t + (t >= 512 ? 1 : 0);
  float acc = ab3[0];
#pragma unroll 8
  for (int i = 0; i < 64; ++i) {
    const float* row = ws + A2_OFF + (b * 64 + i) * A2_S;
    acc += aw3[i] * 0.5f * (row[s] + row[s + 1]);
  }
  float a = 1.f / (1.f + expf(-acc));
  ws[AT_OFF + b * 1024 + t] = a;
  out[16777216 + b * 1024 + t] = a;
}

// K5: stage B: x = eeg*fs*attn; conv(fw1[64,1,128], pad=64) -> BN -> relu,
// accumulated (unpooled, len 1025) over 16-channel group into Hsum[g][b][o][t]
// block 256 = 8 o-groups x 32 t-groups; thread tile 8o x 4t; grid(9, B, 4)
__global__ __launch_bounds__(256) void k5_proj(
    const float* __restrict__ eeg, const float* __restrict__ fsp,
    const float* __restrict__ fw1, const float* __restrict__ fb1,
    const float* __restrict__ bng, const float* __restrict__ bnb,
    const float* __restrict__ bnm, const float* __restrict__ bnv,
    float* __restrict__ ws) {
  int tt = blockIdx.x, b = blockIdx.y, g = blockIdx.z;
  int t0 = tt * 128;
  int tid = threadIdx.x;
  int og = tid >> 5, tg = tid & 31;
  __shared__ float wl[64 * 128];
  __shared__ float xl[256];
  float fs = fsp[0];
  float sc[8], sh[8];
#pragma unroll
  for (int oo = 0; oo < 8; ++oo) {
    int o = og * 8 + oo;
    float s = bng[o] * rsqrtf(bnv[o] + 1e-5f);
    sc[oo] = s;
    sh[oo] = (fb1[o] - bnm[o]) * s + bnb[o];
  }
  for (int r = 0; r < 32; ++r) wl[tid + 256 * r] = fw1[tid + 256 * r];
  float acc[8][4];
#pragma unroll
  for (int oo = 0; oo < 8; ++oo)
#pragma unroll
    for (int j = 0; j < 4; ++j) acc[oo][j] = 0.f;
  const float* attnw = ws + AT_OFF + b * 1024;
  for (int ci = 0; ci < 16; ++ci) {
    int c = g * 16 + ci;
    __syncthreads();
    if (tid < 255) {
      int xj = t0 - 64 + tid;
      float v = 0.f;
      if (xj >= 0 && xj < 1024) v = eeg[(b * 64 + c) * 1024 + xj] * fs * attnw[xj];
      xl[tid] = v;
    }
    __syncthreads();
    float a_c[8][4];
#pragma unroll
    for (int oo = 0; oo < 8; ++oo)
#pragma unroll
      for (int j = 0; j < 4; ++j) a_c[oo][j] = 0.f;
    for (int k4 = 0; k4 < 32; ++k4) {
      float4 w4[8];
#pragma unroll
      for (int oo = 0; oo < 8; ++oo)
        w4[oo] = *(const float4*)&wl[(og * 8 + oo) * 128 + k4 * 4];
      float4 xa = *(const float4*)&xl[tg * 4 + k4 * 4];
      float4 xb = *(const float4*)&xl[tg * 4 + k4 * 4 + 4];
      float xv[8] = {xa.x, xa.y, xa.z, xa.w, xb.x, xb.y, xb.z, xb.w};
#pragma unroll
      for (int jj = 0; jj < 4; ++jj) {
#pragma unroll
        for (int oo = 0; oo < 8; ++oo) {
          float w = ((const float*)&w4[oo])[jj];
#pragma unroll
          for (int j = 0; j < 4; ++j) a_c[oo][j] += w * xv[jj + j];
        }
      }
    }
#pragma unroll
    for (int oo = 0; oo < 8; ++oo)
#pragma unroll
      for (int j = 0; j < 4; ++j)
        acc[oo][j] += fmaxf(a_c[oo][j] * sc[oo] + sh[oo], 0.f);
  }
#pragma unroll
  for (int oo = 0; oo < 8; ++oo) {
    int o = og * 8 + oo;
#pragma unroll
    for (int j = 0; j < 4; ++j) {
      int tp = t0 + tg * 4 + j;
      if (tp < 1025) ws[HS_OFF + ((g * 16 + b) * 64 + o) * HS_S + tp] = acc[oo][j];
    }
  }
}

// K5b: hbar[b,k,t] = (1/128) * sum_g (Hsum[t] + Hsum[t+1])   (pool + channel mean)
__global__ void k5b_pool(float* __restrict__ ws) {
  int id = blockIdx.x * 256 + threadIdx.x;  // exactly 16*64*1024 threads
  int t = id & 1023, k = (id >> 10) & 63, b = id >> 16;
  float v = 0.f;
#pragma unroll
  for (int g = 0; g < 4; ++g) {
    const float* row = ws + HS_OFF + ((g * 16 + b) * 64 + k) * HS_S;
    v += row[t] + row[t + 1];
  }
  ws[HB_OFF + (b * 64 + k) * 1024 + t] = v * (1.f / 128.f);
}

// K6: feats[b,d,t] = sum_k fw2[d,k]*hbar[b,k,t] + fb2[d]
// block 256 = 16 d-groups x 16 t-groups; thread tile 8d x 4t; grid(16 tt, 8 dt, B)
__global__ __launch_bounds__(256) void k6_out(const float* __restrict__ fw2,
                                              const float* __restrict__ fb2,
                                              const float* __restrict__ ws,
                                              float* __restrict__ out) {
  int tt = blockIdx.x, dt = blockIdx.y, b = blockIdx.z;
  int tid = threadIdx.x;
  int dg = tid >> 4, tg = tid & 15;
  __shared__ float wl[128 * 68];
  __shared__ float hbl[64 * 68];
  for (int r = 0; r < 32; ++r) {
    int e = tid + 256 * r;  // 8192
    int dl = e >> 6, k = e & 63;
    wl[dl * 68 + k] = fw2[(dt * 128 + dl) * 64 + k];
  }
  for (int r = 0; r < 16; ++r) {
    int e = tid + 256 * r;  // 4096
    int k = e >> 6, tl = e & 63;
    hbl[tl * 68 + k] = ws[HB_OFF + (b * 64 + k) * 1024 + tt * 64 + tl];
  }
  __syncthreads();
  float acc[8][4];
#pragma unroll
  for (int dd = 0; dd < 8; ++dd)
#pragma unroll
    for (int j = 0; j < 4; ++j) acc[dd][j] = 0.f;
  for (int k4 = 0; k4 < 16; ++k4) {
    float4 w4[8], h4[4];
#pragma unroll
    for (int dd = 0; dd < 8; ++dd)
      w4[dd] = *(const float4*)&wl[(dg * 8 + dd) * 68 + k4 * 4];
#pragma unroll
    for (int j = 0; j < 4; ++j)
      h4[j] = *(const float4*)&hbl[(tg * 4 + j) * 68 + k4 * 4];
#pragma unroll
    for (int dd = 0; dd < 8; ++dd)
#pragma unroll
      for (int j = 0; j < 4; ++j)
        acc[dd][j] += w4[dd].x * h4[j].x + w4[dd].y * h4[j].y +
                      w4[dd].z * h4[j].z + w4[dd].w * h4[j].w;
  }
#pragma unroll
  for (int dd = 0; dd < 8; ++dd) {
    int d = dt * 128 + dg * 8 + dd;
    float bias = fb2[d];
    float4 o4;
    o4.x = acc[dd][0] + bias;
    o4.y = acc[dd][1] + bias;
    o4.z = acc[dd][2] + bias;
    o4.w = acc[dd][3] + bias;
    *(float4*)&out[(b * 1024 + d) * 1024 + tt * 64 + tg * 4] = o4;
  }
}

extern "C" void kernel_launch(void* const* d_in, const int* in_sizes, int n_in,
                              void* d_out, int out_size, void* d_ws, size_t ws_size,
                              hipStream_t stream) {
  const float* eeg = (const float*)d_in[0];
  const float* fsp = (const float*)d_in[1];
  const float* aw1 = (const float*)d_in[2];
  const float* ab1 = (const float*)d_in[3];
  const float* aw2 = (const float*)d_in[4];
  const float* ab2 = (const float*)d_in[5];
  const float* aw3 = (const float*)d_in[6];
  const float* ab3 = (const float*)d_in[7];
  const float* fw1 = (const float*)d_in[8];
  const float* fb1 = (const float*)d_in[9];
  const float* bng = (const float*)d_in[10];
  const float* bnb = (const float*)d_in[11];
  const float* bnm = (const float*)d_in[12];
  const float* bnv = (const float*)d_in[13];
  const float* fw2 = (const float*)d_in[14];
  const float* fb2 = (const float*)d_in[15];
  float* out = (float*)d_out;
  float* ws = (float*)d_ws;

  hipLaunchKernelGGL(k0_zero, dim3(98), dim3(256), 0, stream, ws);
  hipLaunchKernelGGL(k1_ca, dim3(4, 16), dim3(256), 0, stream, eeg, fsp, ws);
  hipLaunchKernelGGL(k2_conv1, dim3(5, 32, 16), dim3(256), 0, stream, aw1, ab1, ws);
  hipLaunchKernelGGL(k3_conv2, dim3(17, 16, 2), dim3(64, 4), 0, stream, aw2, ab2, ws);
  hipLaunchKernelGGL(k4_attn, dim3(4, 16), dim3(256), 0, stream, aw3, ab3, ws, out);
  hipLaunchKernelGGL(k5_proj, dim3(9, 16, 4), dim3(256), 0, stream,
                     eeg, fsp, fw1, fb1, bng, bnb, bnm, bnv, ws);
  hipLaunchKernelGGL(k5b_pool, dim3(4096), dim3(256), 0, stream, ws);
  hipLaunchKernelGGL(k6_out, dim3(16, 8, 16), dim3(256), 0, stream, fw2, fb2, ws, out);
}

// Round 2
// 371.172 us; speedup vs baseline: 1.6878x; 1.6878x over previous
//
#include <hip/hip_runtime.h>
#include <math.h>

#define Bn 16
#define Cn 64
#define Tn 1024
#define Dn 1024

// ---- workspace layout (float element offsets) ----
#define CA_S   1088
#define CA_OFF 0                                 // [B][1088], end 17408
#define AT_OFF 17408                             // attn [B][1024], end 33792
#define SA_OFF 33792                             // sigmoid-acc [B][1024], end 50176
#define A1_S   1072
#define A1_OFF 50176                             // [B*32][1072], end 599040
#define A2_S   1026
#define A2_OFF 599040                            // [B*64][1026], end 1649664
// XS overlays A1/A2 (dead after k4a/k4c): bf16 [4 shifts][B][C][1280]
#define XS_OFF 50176                             // float off; ushort base = 2*XS_OFF
#define XS_U   (2*XS_OFF)
#define HS_S   1040
#define HS_OFF 2671616                           // [2][B][64][1040], end 4801536
#define HB_OFF 4801536                           // [B][64][1024], end 5850112 (23.4 MB)

typedef __attribute__((ext_vector_type(4))) float f32x4;
typedef __attribute__((ext_vector_type(8))) short bf16x8;
typedef __attribute__((ext_vector_type(4))) unsigned int u32x4;

static __device__ inline unsigned short f2bf(float x) {
  unsigned u = __builtin_bit_cast(unsigned, x);
  return (unsigned short)((u + 0x7fffu + ((u >> 16) & 1u)) >> 16);
}

// K0: zero CA, SA, A1 pads
__global__ void k0_zero(float* ws) {
  int id = blockIdx.x * 256 + threadIdx.x;
  if (id < 17408) {
    ws[CA_OFF + id] = 0.f;
  } else if (id < 33792) {
    ws[SA_OFF + (id - 17408)] = 0.f;
  } else if (id < 57856) {
    int id2 = id - 33792;
    int row = id2 / 47, j = id2 % 47;
    int pos = (j < 16) ? j : (1041 + j - 16);
    ws[A1_OFF + row * A1_S + pos] = 0.f;
  }
}

// K1: ca[b,t] += fs/64 * sum_{8 ch} eeg  (atomic partial sums, 512 blocks)
__global__ void k1_ca(const float* __restrict__ eeg, const float* __restrict__ fsp,
                      float* __restrict__ ws) {
  int b = blockIdx.y, t = blockIdx.x * 256 + threadIdx.x;
  int c0 = blockIdx.z * 8;
  float s = 0.f;
#pragma unroll
  for (int j = 0; j < 8; ++j) s += eeg[(b * 64 + c0 + j) * 1024 + t];
  atomicAdd(&ws[CA_OFF + b * CA_S + 32 + t], s * fsp[0] * (1.f / 64.f));
}

// K2: a1 = relu(conv1d(ca, aw1[32,1,64], pad=32)), len 1025
__global__ void k2_conv1(const float* __restrict__ aw1, const float* __restrict__ ab1,
                         float* __restrict__ ws) {
  int t = blockIdx.x * 256 + threadIdx.x;
  int o = blockIdx.y, b = blockIdx.z;
  if (t >= 1025) return;
  const float* cab = ws + CA_OFF + b * CA_S;
  float acc = ab1[o];
#pragma unroll 8
  for (int k = 0; k < 64; ++k) acc += aw1[o * 64 + k] * cab[t + k];
  ws[A1_OFF + (b * 32 + o) * A1_S + 16 + t] = fmaxf(acc, 0.f);
}

// K3: a2 = relu(conv1d(a1, aw2[64,32,32], pad=16)), len 1026
__global__ __launch_bounds__(256) void k3_conv2(const float* __restrict__ aw2,
                                                const float* __restrict__ ab2,
                                                float* __restrict__ ws) {
  int tx = threadIdx.x, ty = threadIdx.y;
  int t0 = blockIdx.x * 64, b = blockIdx.y, oh = blockIdx.z;
  __shared__ float xl[32 * 96];
  int tid = ty * 64 + tx;
  for (int r = 0; r < 12; ++r) {
    int e = tid + 256 * r;
    if (e < 32 * 95) {
      int i = e / 95, j = e % 95;
      int idx = t0 + j;
      xl[i * 96 + j] = (idx < A1_S) ? ws[A1_OFF + (b * 32 + i) * A1_S + idx] : 0.f;
    }
  }
  __syncthreads();
  int obase = oh * 32 + ty * 8;
  float acc[8];
#pragma unroll
  for (int oo = 0; oo < 8; ++oo) acc[oo] = ab2[obase + oo];
  for (int i = 0; i < 32; ++i) {
#pragma unroll
    for (int k4 = 0; k4 < 8; ++k4) {
      float4 w4[8];
#pragma unroll
      for (int oo = 0; oo < 8; ++oo)
        w4[oo] = *(const float4*)&aw2[((obase + oo) * 32 + i) * 32 + k4 * 4];
      float xv[4];
#pragma unroll
      for (int j = 0; j < 4; ++j) xv[j] = xl[i * 96 + tx + k4 * 4 + j];
#pragma unroll
      for (int oo = 0; oo < 8; ++oo)
        acc[oo] += w4[oo].x * xv[0] + w4[oo].y * xv[1] + w4[oo].z * xv[2] + w4[oo].w * xv[3];
    }
  }
  int t2 = t0 + tx;
  if (t2 < 1026) {
#pragma unroll
    for (int oo = 0; oo < 8; ++oo)
      ws[A2_OFF + (b * 64 + obase + oo) * A2_S + t2] = fmaxf(acc[oo], 0.f);
  }
}

// K4a: partial (16 of 64 rows) of pooled 1x1 conv -> atomicAdd into SA
__global__ void k4a_part(const float* __restrict__ aw3, float* __restrict__ ws) {
  int b = blockIdx.y, t = blockIdx.x * 256 + threadIdx.x;
  int i0 = blockIdx.z * 16;
  int s = t + (t >= 512 ? 1 : 0);
  float acc = 0.f;
#pragma unroll
  for (int ii = 0; ii < 16; ++ii) {
    const float* row = ws + A2_OFF + (b * 64 + i0 + ii) * A2_S;
    acc += aw3[i0 + ii] * 0.5f * (row[s] + row[s + 1]);
  }
  atomicAdd(&ws[SA_OFF + b * 1024 + t], acc);
}

// K4c: sigmoid -> attn in ws + second output
__global__ void k4c_sig(const float* __restrict__ ab3, float* __restrict__ ws,
                        float* __restrict__ out) {
  int b = blockIdx.y, t = blockIdx.x * 256 + threadIdx.x;
  float a = 1.f / (1.f + expf(-(ws[SA_OFF + b * 1024 + t] + ab3[0])));
  ws[AT_OFF + b * 1024 + t] = a;
  out[16777216 + b * 1024 + t] = a;
}

// K4b: build 4 shifted bf16 copies of xs_pad = pad64(eeg*fs*attn), row len 1280
__global__ void k4b_xs(const float* __restrict__ eeg, const float* __restrict__ fsp,
                       float* __restrict__ ws) {
  int bc = blockIdx.x;          // b*64 + c
  int b = bc >> 6;
  int tid = threadIdx.x;
  __shared__ unsigned short xsl[1288];
  float fs = fsp[0];
  for (int i = tid; i < 1288; i += 256) {
    int j = i - 64;
    float v = 0.f;
    if (j >= 0 && j < 1024) v = eeg[bc * 1024 + j] * fs * ws[AT_OFF + b * 1024 + j];
    xsl[i] = f2bf(v);
  }
  __syncthreads();
  unsigned short* xsg = (unsigned short*)ws + XS_U;
  for (int q = tid; q < 640; q += 256) {
    int s = q / 160, m = q % 160, e = m * 8;
    uint4 v;
    unsigned a0 = xsl[e + s + 0], a1 = xsl[e + s + 1], a2 = xsl[e + s + 2], a3 = xsl[e + s + 3];
    unsigned a4 = xsl[e + s + 4], a5 = xsl[e + s + 5], a6 = xsl[e + s + 6], a7 = xsl[e + s + 7];
    v.x = a0 | (a1 << 16); v.y = a2 | (a3 << 16); v.z = a4 | (a5 << 16); v.w = a6 | (a7 << 16);
    *(uint4*)&xsg[(s * 1024 + bc) * 1280 + e] = v;
  }
}

// K5: MFMA stage-B conv. Block: 4 waves, 64 t's, 32 channels, o=64, K=128.
// grid(17 t-tiles, B, 2 ch-halves). Writes unpooled Hsum[g2][b][o][t], t<=1024.
__global__ __launch_bounds__(256, 2) void k5_mfma(
    const float* __restrict__ fw1, const float* __restrict__ fb1,
    const float* __restrict__ bng, const float* __restrict__ bnb,
    const float* __restrict__ bnm, const float* __restrict__ bnv,
    float* __restrict__ ws) {
  int t0 = blockIdx.x * 64, b = blockIdx.y, g2 = blockIdx.z;
  int tid = threadIdx.x, l = tid & 63, w = tid >> 6;
  __shared__ unsigned short wlds[64 * 128];
  __shared__ unsigned short xlds[32 * 4 * 200];

  // stage weights (fp32 -> bf16), 8192 elems, 32/thread
  {
    int e0 = tid * 32;
#pragma unroll
    for (int j = 0; j < 8; ++j) {
      float4 f = *(const float4*)&fw1[e0 + j * 4];
      wlds[e0 + j * 4 + 0] = f2bf(f.x);
      wlds[e0 + j * 4 + 1] = f2bf(f.y);
      wlds[e0 + j * 4 + 2] = f2bf(f.z);
      wlds[e0 + j * 4 + 3] = f2bf(f.w);
    }
  }
  // stage xs: 32 ch x 4 copies x 192 elems (12 x uint4 per thread)
  const unsigned short* xsg = (const unsigned short*)ws + XS_U;
#pragma unroll
  for (int r = 0; r < 12; ++r) {
    int q = tid + r * 256;
    int ch = q / 96, rem = q % 96, s = rem / 24, m = rem % 24;
    int c = g2 * 32 + ch;
    uint4 v = *(const uint4*)&xsg[((s * 1024) + b * 64 + c) * 1280 + t0 + m * 8];
    *(uint4*)&xlds[(ch * 4 + s) * 200 + m * 8] = v;
  }
  // BN constants per lane
  int row0 = (l >> 4) * 4;
  float scv[4][4], shv[4][4];
#pragma unroll
  for (int mt = 0; mt < 4; ++mt)
#pragma unroll
    for (int r = 0; r < 4; ++r) {
      int o = mt * 16 + row0 + r;
      float s = bng[o] * rsqrtf(bnv[o] + 1e-5f);
      scv[mt][r] = s;
      shv[mt][r] = (fb1[o] - bnm[o]) * s + bnb[o];
    }
  __syncthreads();

  // weight fragments -> registers: A[m][k], lane row=l&15, k=(l>>4)*8+r
  u32x4 wf[4][4];
#pragma unroll
  for (int mt = 0; mt < 4; ++mt)
#pragma unroll
    for (int ks = 0; ks < 4; ++ks)
      wf[mt][ks] = *(const u32x4*)&wlds[(mt * 16 + (l & 15)) * 128 + ks * 32 + (l >> 4) * 8];

  // precompute per-lane x-frag offsets (within a channel's 4x200 region)
  int xoff[4];
#pragma unroll
  for (int ks = 0; ks < 4; ++ks) {
    int A0 = (l & 15) + ks * 32 + (l >> 4) * 8;
    int s = A0 & 3, e = A0 & ~3;
    xoff[ks] = s * 200 + w * 16 + e;
  }

  f32x4 acc[4];
#pragma unroll
  for (int mt = 0; mt < 4; ++mt) acc[mt] = (f32x4){0.f, 0.f, 0.f, 0.f};

  for (int ch = 0; ch < 32; ++ch) {
    u32x4 bf[4];
#pragma unroll
    for (int ks = 0; ks < 4; ++ks) {
      const uint2* p = (const uint2*)&xlds[ch * 800 + xoff[ks]];
      uint2 lo = p[0], hi = p[1];
      u32x4 bb; bb.x = lo.x; bb.y = lo.y; bb.z = hi.x; bb.w = hi.y;
      bf[ks] = bb;
    }
#pragma unroll
    for (int mt = 0; mt < 4; ++mt) {
      f32x4 c = (f32x4){0.f, 0.f, 0.f, 0.f};
#pragma unroll
      for (int ks = 0; ks < 4; ++ks)
        c = __builtin_amdgcn_mfma_f32_16x16x32_bf16(
            __builtin_bit_cast(bf16x8, wf[mt][ks]),
            __builtin_bit_cast(bf16x8, bf[ks]), c, 0, 0, 0);
#pragma unroll
      for (int r = 0; r < 4; ++r)
        acc[mt][r] += fmaxf(c[r] * scv[mt][r] + shv[mt][r], 0.f);
    }
  }
  int t = t0 + w * 16 + (l & 15);
  if (t < 1025) {
#pragma unroll
    for (int mt = 0; mt < 4; ++mt)
#pragma unroll
      for (int r = 0; r < 4; ++r)
        ws[HS_OFF + (((g2 * 16 + b) * 64) + mt * 16 + row0 + r) * HS_S + t] = acc[mt][r];
  }
}

// K5b: hbar[b,k,t] = 1/128 * sum_{g=0,1} (HS[t] + HS[t+1])
__global__ void k5b_pool(float* __restrict__ ws) {
  int id = blockIdx.x * 256 + threadIdx.x;
  int t = id & 1023, k = (id >> 10) & 63, b = id >> 16;
  float v = 0.f;
#pragma unroll
  for (int g = 0; g < 2; ++g) {
    const float* row = ws + HS_OFF + (((g * 16 + b) * 64) + k) * HS_S;
    v += row[t] + row[t + 1];
  }
  ws[HB_OFF + (b * 64 + k) * 1024 + t] = v * (1.f / 128.f);
}

// K6: feats[b,d,t] = sum_k fw2[d,k]*hbar[b,k,t] + fb2[d]
__global__ __launch_bounds__(256) void k6_out(const float* __restrict__ fw2,
                                              const float* __restrict__ fb2,
                                              const float* __restrict__ ws,
                                              float* __restrict__ out) {
  int tt = blockIdx.x, dt = blockIdx.y, b = blockIdx.z;
  int tid = threadIdx.x;
  int dg = tid >> 4, tg = tid & 15;
  __shared__ float wl[128 * 68];
  __shared__ float hbl[64 * 68];
  for (int r = 0; r < 32; ++r) {
    int e = tid + 256 * r;
    int dl = e >> 6, k = e & 63;
    wl[dl * 68 + k] = fw2[(dt * 128 + dl) * 64 + k];
  }
  for (int r = 0; r < 16; ++r) {
    int e = tid + 256 * r;
    int k = e >> 6, tl = e & 63;
    hbl[tl * 68 + k] = ws[HB_OFF + (b * 64 + k) * 1024 + tt * 64 + tl];
  }
  __syncthreads();
  float acc[8][4];
#pragma unroll
  for (int dd = 0; dd < 8; ++dd)
#pragma unroll
    for (int j = 0; j < 4; ++j) acc[dd][j] = 0.f;
  for (int k4 = 0; k4 < 16; ++k4) {
    float4 w4[8], h4[4];
#pragma unroll
    for (int dd = 0; dd < 8; ++dd)
      w4[dd] = *(const float4*)&wl[(dg * 8 + dd) * 68 + k4 * 4];
#pragma unroll
    for (int j = 0; j < 4; ++j)
      h4[j] = *(const float4*)&hbl[(tg * 4 + j) * 68 + k4 * 4];
#pragma unroll
    for (int dd = 0; dd < 8; ++dd)
#pragma unroll
      for (int j = 0; j < 4; ++j)
        acc[dd][j] += w4[dd].x * h4[j].x + w4[dd].y * h4[j].y +
                      w4[dd].z * h4[j].z + w4[dd].w * h4[j].w;
  }
#pragma unroll
  for (int dd = 0; dd < 8; ++dd) {
    int d = dt * 128 + dg * 8 + dd;
    float bias = fb2[d];
    float4 o4;
    o4.x = acc[dd][0] + bias;
    o4.y = acc[dd][1] + bias;
    o4.z = acc[dd][2] + bias;
    o4.w = acc[dd][3] + bias;
    *(float4*)&out[(b * 1024 + d) * 1024 + tt * 64 + tg * 4] = o4;
  }
}

extern "C" void kernel_launch(void* const* d_in, const int* in_sizes, int n_in,
                              void* d_out, int out_size, void* d_ws, size_t ws_size,
                              hipStream_t stream) {
  const float* eeg = (const float*)d_in[0];
  const float* fsp = (const float*)d_in[1];
  const float* aw1 = (const float*)d_in[2];
  const float* ab1 = (const float*)d_in[3];
  const float* aw2 = (const float*)d_in[4];
  const float* ab2 = (const float*)d_in[5];
  const float* aw3 = (const float*)d_in[6];
  const float* ab3 = (const float*)d_in[7];
  const float* fw1 = (const float*)d_in[8];
  const float* fb1 = (const float*)d_in[9];
  const float* bng = (const float*)d_in[10];
  const float* bnb = (const float*)d_in[11];
  const float* bnm = (const float*)d_in[12];
  const float* bnv = (const float*)d_in[13];
  const float* fw2 = (const float*)d_in[14];
  const float* fb2 = (const float*)d_in[15];
  float* out = (float*)d_out;
  float* ws = (float*)d_ws;

  hipLaunchKernelGGL(k0_zero, dim3(226), dim3(256), 0, stream, ws);
  hipLaunchKernelGGL(k1_ca, dim3(4, 16, 8), dim3(256), 0, stream, eeg, fsp, ws);
  hipLaunchKernelGGL(k2_conv1, dim3(5, 32, 16), dim3(256), 0, stream, aw1, ab1, ws);
  hipLaunchKernelGGL(k3_conv2, dim3(17, 16, 2), dim3(64, 4), 0, stream, aw2, ab2, ws);
  hipLaunchKernelGGL(k4a_part, dim3(4, 16, 4), dim3(256), 0, stream, aw3, ws);
  hipLaunchKernelGGL(k4c_sig, dim3(4, 16), dim3(256), 0, stream, ab3, ws, out);
  hipLaunchKernelGGL(k4b_xs, dim3(1024), dim3(256), 0, stream, eeg, fsp, ws);
  hipLaunchKernelGGL(k5_mfma, dim3(17, 16, 2), dim3(256), 0, stream,
                     fw1, fb1, bng, bnb, bnm, bnv, ws);
  hipLaunchKernelGGL(k5b_pool, dim3(4096), dim3(256), 0, stream, ws);
  hipLaunchKernelGGL(k6_out, dim3(16, 8, 16), dim3(256), 0, stream, fw2, fb2, ws, out);
}

// Round 3
// 185.572 us; speedup vs baseline: 3.3758x; 2.0001x over previous
//
#include <hip/hip_runtime.h>
#include <math.h>

#define Bn 16
#define Cn 64
#define Tn 1024
#define Dn 1024

// ---- workspace layout (float element offsets) ----
#define CA_S   1088
#define CA_OFF 0                                 // [B][1088], end 17408
#define AT_OFF 17408                             // attn [B][1024], end 33792
#define SA_OFF 33792                             // sigmoid-acc [B][1024], end 50176
#define A1_S   1072
#define A1_OFF 50176                             // [B*32][1072], end 599040
#define A2_S   1026
#define A2_OFF 599040                            // [B*64][1026], end 1649664
// XS overlays A1/A2 (dead after k3/k4a/k4c): bf16 [4][B][C][1280]
#define XS_U   (2*50176)
#define HS_S   1040
#define HS_OFF 2671616                           // fp32 [2][B][64][1040], end 4801536
#define HB_OFF 4801536                           // (region reused, see ushort offsets)

// ---- ushort offsets ----
#define A1S_U  (2*HS_OFF)                        // bf16 a1 shifted copies [4][512][1216] (overlays HS; dead before k5)
#define HBT_U  (2*HB_OFF)                        // bf16 hbT [B][1024 t][64 k] = 1048576
#define WFW2_U (HBT_U + 1048576)                 // bf16 fw2 [1024][64]
#define WAW2_U (WFW2_U + 65536)                  // bf16 aw2 [64][32][32]
#define WFW1_U (WAW2_U + 65536)                  // bf16 fw1 [64][128]

typedef __attribute__((ext_vector_type(4))) float f32x4;
typedef __attribute__((ext_vector_type(8))) short bf16x8;
typedef __attribute__((ext_vector_type(4))) unsigned int u32x4;

static __device__ inline unsigned short f2bf(float x) {
  unsigned u = __builtin_bit_cast(unsigned, x);
  return (unsigned short)((u + 0x7fffu + ((u >> 16) & 1u)) >> 16);
}

// K0: zero CA, SA, A1 pads; convert aw2/fw2/fw1 -> bf16
__global__ void k0_zero(const float* __restrict__ aw2, const float* __restrict__ fw2,
                        const float* __restrict__ fw1, float* __restrict__ ws) {
  int id = blockIdx.x * 256 + threadIdx.x;
  if (id < 17408) {
    ws[CA_OFF + id] = 0.f;
  } else if (id < 33792) {
    ws[SA_OFF + (id - 17408)] = 0.f;
  } else if (id < 57856) {
    int id2 = id - 33792;
    int row = id2 / 47, j = id2 % 47;
    int pos = (j < 16) ? j : (1041 + j - 16);
    ws[A1_OFF + row * A1_S + pos] = 0.f;
  } else if (id < 74240) {
    int e0 = (id - 57856) * 4;
    float4 f = *(const float4*)&aw2[e0];
    unsigned short* d = (unsigned short*)ws + WAW2_U + e0;
    d[0] = f2bf(f.x); d[1] = f2bf(f.y); d[2] = f2bf(f.z); d[3] = f2bf(f.w);
  } else if (id < 90624) {
    int e0 = (id - 74240) * 4;
    float4 f = *(const float4*)&fw2[e0];
    unsigned short* d = (unsigned short*)ws + WFW2_U + e0;
    d[0] = f2bf(f.x); d[1] = f2bf(f.y); d[2] = f2bf(f.z); d[3] = f2bf(f.w);
  } else if (id < 92672) {
    int e0 = (id - 90624) * 4;
    float4 f = *(const float4*)&fw1[e0];
    unsigned short* d = (unsigned short*)ws + WFW1_U + e0;
    d[0] = f2bf(f.x); d[1] = f2bf(f.y); d[2] = f2bf(f.z); d[3] = f2bf(f.w);
  }
}

// K1: ca[b,t] += fs/64 * sum_{8 ch} eeg
__global__ void k1_ca(const float* __restrict__ eeg, const float* __restrict__ fsp,
                      float* __restrict__ ws) {
  int b = blockIdx.y, t = blockIdx.x * 256 + threadIdx.x;
  int c0 = blockIdx.z * 8;
  float s = 0.f;
#pragma unroll
  for (int j = 0; j < 8; ++j) s += eeg[(b * 64 + c0 + j) * 1024 + t];
  atomicAdd(&ws[CA_OFF + b * CA_S + 32 + t], s * fsp[0] * (1.f / 64.f));
}

// K2: a1 = relu(conv1d(ca, aw1[32,1,64], pad=32)), len 1025
__global__ void k2_conv1(const float* __restrict__ aw1, const float* __restrict__ ab1,
                         float* __restrict__ ws) {
  int t = blockIdx.x * 256 + threadIdx.x;
  int o = blockIdx.y, b = blockIdx.z;
  if (t >= 1025) return;
  const float* cab = ws + CA_OFF + b * CA_S;
  float acc = ab1[o];
#pragma unroll 8
  for (int k = 0; k < 64; ++k) acc += aw1[o * 64 + k] * cab[t + k];
  ws[A1_OFF + (b * 32 + o) * A1_S + 16 + t] = fmaxf(acc, 0.f);
}

// K2b: build 4 shifted bf16 copies of a1 rows (len 1216, zeros beyond data)
__global__ void k2b_a1s(float* __restrict__ ws) {
  int row = blockIdx.x;  // b*32 + i, 512 rows
  int tid = threadIdx.x;
  __shared__ unsigned short xl[1232];
  const float* src = ws + A1_OFF + row * A1_S;
  for (int i = tid; i < 1232; i += 256) {
    float v = (i < 1072) ? src[i] : 0.f;
    xl[i] = f2bf(v);
  }
  __syncthreads();
  unsigned short* a1s = (unsigned short*)ws + A1S_U;
  for (int q = tid; q < 608; q += 256) {
    int s = q / 152, mm = q % 152;
    int e = mm * 8;
    unsigned a0 = xl[e + s + 0], a1 = xl[e + s + 1], a2 = xl[e + s + 2], a3 = xl[e + s + 3];
    unsigned a4 = xl[e + s + 4], a5 = xl[e + s + 5], a6 = xl[e + s + 6], a7 = xl[e + s + 7];
    uint4 v;
    v.x = a0 | (a1 << 16); v.y = a2 | (a3 << 16); v.z = a4 | (a5 << 16); v.w = a6 | (a7 << 16);
    *(uint4*)&a1s[(s * 512 + row) * 1216 + e] = v;
  }
}

// K3: MFMA conv2. Block: 4 waves x 16 t = 64 t, 16 outputs, K = 32 i x 32 kk.
// grid(17, B, 4 o-quarters). Writes a2 fp32 [b][o][1026].
__global__ __launch_bounds__(256) void k3_mfma(const float* __restrict__ ab2,
                                               float* __restrict__ ws) {
  int t0 = blockIdx.x * 64, b = blockIdx.y, oh = blockIdx.z;
  int tid = threadIdx.x, l = tid & 63, w = tid >> 6;
  __shared__ unsigned short wlds[16 * 1032];   // [o16][i*32+kk], stride 1032 (pad)
  __shared__ unsigned short xlds[32 * 4 * 104];  // [i][s][104], 96 used
  const unsigned short* wb = (const unsigned short*)ws + WAW2_U;
  const unsigned short* a1s = (const unsigned short*)ws + A1S_U;
#pragma unroll
  for (int r = 0; r < 8; ++r) {
    int idx = tid + r * 256;       // 2048 uint4
    int o = idx >> 7, j = idx & 127;
    *(uint4*)&wlds[o * 1032 + j * 8] = *(const uint4*)&wb[(oh * 16 + o) * 1024 + j * 8];
  }
#pragma unroll
  for (int r = 0; r < 6; ++r) {
    int idx = tid + r * 256;       // 1536 uint4
    int i = idx / 48, rem = idx % 48, s = rem / 12, mm = rem % 12;
    *(uint4*)&xlds[(i * 4 + s) * 104 + mm * 8] =
        *(const uint4*)&a1s[(s * 512 + b * 32 + i) * 1216 + t0 + mm * 8];
  }
  __syncthreads();
  int m = l & 15, q = l >> 4;
  int A0 = w * 16 + m + q * 8;
  int xoffb = (A0 & 3) * 104 + (A0 & ~3);
  f32x4 acc = (f32x4){0.f, 0.f, 0.f, 0.f};
  for (int i = 0; i < 32; ++i) {
    const uint2* p = (const uint2*)&xlds[i * 416 + xoffb];
    uint2 lo = p[0], hi = p[1];
    u32x4 bb; bb.x = lo.x; bb.y = lo.y; bb.z = hi.x; bb.w = hi.y;
    u32x4 a = *(const u32x4*)&wlds[m * 1032 + i * 32 + q * 8];
    acc = __builtin_amdgcn_mfma_f32_16x16x32_bf16(
        __builtin_bit_cast(bf16x8, a), __builtin_bit_cast(bf16x8, bb), acc, 0, 0, 0);
  }
  int t = t0 + w * 16 + m;
  if (t < 1026) {
#pragma unroll
    for (int r = 0; r < 4; ++r) {
      int o = oh * 16 + q * 4 + r;
      ws[A2_OFF + (b * 64 + o) * A2_S + t] = fmaxf(acc[r] + ab2[o], 0.f);
    }
  }
}

// K4a: partial (16 of 64 rows) of pooled 1x1 conv -> atomicAdd into SA
__global__ void k4a_part(const float* __restrict__ aw3, float* __restrict__ ws) {
  int b = blockIdx.y, t = blockIdx.x * 256 + threadIdx.x;
  int i0 = blockIdx.z * 16;
  int s = t + (t >= 512 ? 1 : 0);
  float acc = 0.f;
#pragma unroll
  for (int ii = 0; ii < 16; ++ii) {
    const float* row = ws + A2_OFF + (b * 64 + i0 + ii) * A2_S;
    acc += aw3[i0 + ii] * 0.5f * (row[s] + row[s + 1]);
  }
  atomicAdd(&ws[SA_OFF + b * 1024 + t], acc);
}

// K4c: sigmoid -> attn in ws + second output
__global__ void k4c_sig(const float* __restrict__ ab3, float* __restrict__ ws,
                        float* __restrict__ out) {
  int b = blockIdx.y, t = blockIdx.x * 256 + threadIdx.x;
  float a = 1.f / (1.f + expf(-(ws[SA_OFF + b * 1024 + t] + ab3[0])));
  ws[AT_OFF + b * 1024 + t] = a;
  out[16777216 + b * 1024 + t] = a;
}

// K4b: build 4 shifted bf16 copies of xs_pad = pad64(eeg*fs*attn), row len 1280
__global__ void k4b_xs(const float* __restrict__ eeg, const float* __restrict__ fsp,
                       float* __restrict__ ws) {
  int bc = blockIdx.x;
  int b = bc >> 6;
  int tid = threadIdx.x;
  __shared__ unsigned short xsl[1288];
  float fs = fsp[0];
  for (int i = tid; i < 1288; i += 256) {
    int j = i - 64;
    float v = 0.f;
    if (j >= 0 && j < 1024) v = eeg[bc * 1024 + j] * fs * ws[AT_OFF + b * 1024 + j];
    xsl[i] = f2bf(v);
  }
  __syncthreads();
  unsigned short* xsg = (unsigned short*)ws + XS_U;
  for (int q = tid; q < 640; q += 256) {
    int s = q / 160, m = q % 160, e = m * 8;
    uint4 v;
    unsigned a0 = xsl[e + s + 0], a1 = xsl[e + s + 1], a2 = xsl[e + s + 2], a3 = xsl[e + s + 3];
    unsigned a4 = xsl[e + s + 4], a5 = xsl[e + s + 5], a6 = xsl[e + s + 6], a7 = xsl[e + s + 7];
    v.x = a0 | (a1 << 16); v.y = a2 | (a3 << 16); v.z = a4 | (a5 << 16); v.w = a6 | (a7 << 16);
    *(uint4*)&xsg[(s * 1024 + bc) * 1280 + e] = v;
  }
}

// K5: MFMA stage-B conv (unchanged except bf16 weight staging)
__global__ __launch_bounds__(256, 2) void k5_mfma(
    const float* __restrict__ fb1,
    const float* __restrict__ bng, const float* __restrict__ bnb,
    const float* __restrict__ bnm, const float* __restrict__ bnv,
    float* __restrict__ ws) {
  int t0 = blockIdx.x * 64, b = blockIdx.y, g2 = blockIdx.z;
  int tid = threadIdx.x, l = tid & 63, w = tid >> 6;
  __shared__ unsigned short wlds[64 * 128];
  __shared__ unsigned short xlds[32 * 4 * 200];
  const unsigned short* wbf = (const unsigned short*)ws + WFW1_U;
#pragma unroll
  for (int r = 0; r < 4; ++r) {
    int idx = tid + r * 256;  // 1024 uint4
    *(uint4*)&wlds[idx * 8] = *(const uint4*)&wbf[idx * 8];
  }
  const unsigned short* xsg = (const unsigned short*)ws + XS_U;
#pragma unroll
  for (int r = 0; r < 12; ++r) {
    int q = tid + r * 256;
    int ch = q / 96, rem = q % 96, s = rem / 24, m = rem % 24;
    int c = g2 * 32 + ch;
    uint4 v = *(const uint4*)&xsg[((s * 1024) + b * 64 + c) * 1280 + t0 + m * 8];
    *(uint4*)&xlds[(ch * 4 + s) * 200 + m * 8] = v;
  }
  int row0 = (l >> 4) * 4;
  float scv[4][4], shv[4][4];
#pragma unroll
  for (int mt = 0; mt < 4; ++mt)
#pragma unroll
    for (int r = 0; r < 4; ++r) {
      int o = mt * 16 + row0 + r;
      float s = bng[o] * rsqrtf(bnv[o] + 1e-5f);
      scv[mt][r] = s;
      shv[mt][r] = (fb1[o] - bnm[o]) * s + bnb[o];
    }
  __syncthreads();
  u32x4 wf[4][4];
#pragma unroll
  for (int mt = 0; mt < 4; ++mt)
#pragma unroll
    for (int ks = 0; ks < 4; ++ks)
      wf[mt][ks] = *(const u32x4*)&wlds[(mt * 16 + (l & 15)) * 128 + ks * 32 + (l >> 4) * 8];
  int xoff[4];
#pragma unroll
  for (int ks = 0; ks < 4; ++ks) {
    int A0 = (l & 15) + ks * 32 + (l >> 4) * 8;
    int s = A0 & 3, e = A0 & ~3;
    xoff[ks] = s * 200 + w * 16 + e;
  }
  f32x4 acc[4];
#pragma unroll
  for (int mt = 0; mt < 4; ++mt) acc[mt] = (f32x4){0.f, 0.f, 0.f, 0.f};
  for (int ch = 0; ch < 32; ++ch) {
    u32x4 bf[4];
#pragma unroll
    for (int ks = 0; ks < 4; ++ks) {
      const uint2* p = (const uint2*)&xlds[ch * 800 + xoff[ks]];
      uint2 lo = p[0], hi = p[1];
      u32x4 bb; bb.x = lo.x; bb.y = lo.y; bb.z = hi.x; bb.w = hi.y;
      bf[ks] = bb;
    }
#pragma unroll
    for (int mt = 0; mt < 4; ++mt) {
      f32x4 c = (f32x4){0.f, 0.f, 0.f, 0.f};
#pragma unroll
      for (int ks = 0; ks < 4; ++ks)
        c = __builtin_amdgcn_mfma_f32_16x16x32_bf16(
            __builtin_bit_cast(bf16x8, wf[mt][ks]),
            __builtin_bit_cast(bf16x8, bf[ks]), c, 0, 0, 0);
#pragma unroll
      for (int r = 0; r < 4; ++r)
        acc[mt][r] += fmaxf(c[r] * scv[mt][r] + shv[mt][r], 0.f);
    }
  }
  int t = t0 + w * 16 + (l & 15);
  if (t < 1025) {
#pragma unroll
    for (int mt = 0; mt < 4; ++mt)
#pragma unroll
      for (int r = 0; r < 4; ++r)
        ws[HS_OFF + (((g2 * 16 + b) * 64) + mt * 16 + row0 + r) * HS_S + t] = acc[mt][r];
  }
}

// K5b: pool + channel-mean + transpose -> hbT[b][t][k] bf16
__global__ void k5b_t(float* __restrict__ ws) {
  int tt = blockIdx.x, b = blockIdx.y;
  int tid = threadIdx.x;
  __shared__ unsigned short tr[64 * 80];  // [t_local][k], stride 80
  int k = tid >> 2, q = tid & 3;
  const float* r0 = ws + HS_OFF + ((0 + b) * 64 + k) * HS_S + tt * 64;
  const float* r1 = ws + HS_OFF + ((16 + b) * 64 + k) * HS_S + tt * 64;
#pragma unroll
  for (int j = 0; j < 16; ++j) {
    int tl = q * 16 + j;
    float v = r0[tl] + r0[tl + 1] + r1[tl] + r1[tl + 1];
    tr[tl * 80 + k] = f2bf(v * (1.f / 128.f));
  }
  __syncthreads();
  unsigned short* hbT = (unsigned short*)ws + HBT_U;
#pragma unroll
  for (int r = 0; r < 2; ++r) {
    int idx = tid + r * 256;  // 512 uint4
    int tl = idx >> 3, j = idx & 7;
    uint4 v = *(uint4*)&tr[tl * 80 + j * 8];
    *(uint4*)&hbT[(b * 1024 + tt * 64 + tl) * 64 + j * 8] = v;
  }
}

// K6: MFMA out-GEMM: out[b][d][t] = sum_k fw2[d][k]*hb[k][t] + fb2[d]
// block 64d x 64t, 4 waves (2x2), each 32d x 32t. grid(16 tt, 16 dt, B)
__global__ __launch_bounds__(256) void k6_mfma(const float* __restrict__ fb2,
                                               float* __restrict__ ws,
                                               float* __restrict__ out) {
  int tt = blockIdx.x, dt = blockIdx.y, b = blockIdx.z;
  int tid = threadIdx.x, l = tid & 63, w = tid >> 6;
  int wd = w >> 1, wt = w & 1;
  __shared__ unsigned short wA[64 * 80], xB[64 * 80];
  const unsigned short* w2 = (const unsigned short*)ws + WFW2_U;
  const unsigned short* hbT = (const unsigned short*)ws + HBT_U;
#pragma unroll
  for (int r = 0; r < 2; ++r) {
    int idx = tid + r * 256;  // 512
    int row = idx >> 3, j = idx & 7;
    *(uint4*)&wA[row * 80 + j * 8] = *(const uint4*)&w2[(dt * 64 + row) * 64 + j * 8];
    *(uint4*)&xB[row * 80 + j * 8] = *(const uint4*)&hbT[(b * 1024 + tt * 64 + row) * 64 + j * 8];
  }
  __syncthreads();
  int m = l & 15, q = l >> 4;
  f32x4 acc[2][2];
#pragma unroll
  for (int mt = 0; mt < 2; ++mt)
#pragma unroll
    for (int nt = 0; nt < 2; ++nt) acc[mt][nt] = (f32x4){0.f, 0.f, 0.f, 0.f};
#pragma unroll
  for (int ks = 0; ks < 2; ++ks) {
    u32x4 a[2], bb[2];
#pragma unroll
    for (int mt = 0; mt < 2; ++mt)
      a[mt] = *(const u32x4*)&wA[(wd * 32 + mt * 16 + m) * 80 + ks * 32 + q * 8];
#pragma unroll
    for (int nt = 0; nt < 2; ++nt)
      bb[nt] = *(const u32x4*)&xB[(wt * 32 + nt * 16 + m) * 80 + ks * 32 + q * 8];
#pragma unroll
    for (int mt = 0; mt < 2; ++mt)
#pragma unroll
      for (int nt = 0; nt < 2; ++nt)
        acc[mt][nt] = __builtin_amdgcn_mfma_f32_16x16x32_bf16(
            __builtin_bit_cast(bf16x8, a[mt]), __builtin_bit_cast(bf16x8, bb[nt]),
            acc[mt][nt], 0, 0, 0);
  }
#pragma unroll
  for (int mt = 0; mt < 2; ++mt) {
#pragma unroll
    for (int r = 0; r < 4; ++r) {
      int d = dt * 64 + wd * 32 + mt * 16 + q * 4 + r;
      float bias = fb2[d];
#pragma unroll
      for (int nt = 0; nt < 2; ++nt) {
        int t = tt * 64 + wt * 32 + nt * 16 + m;
        out[(b * 1024 + d) * 1024 + t] = acc[mt][nt][r] + bias;
      }
    }
  }
}

extern "C" void kernel_launch(void* const* d_in, const int* in_sizes, int n_in,
                              void* d_out, int out_size, void* d_ws, size_t ws_size,
                              hipStream_t stream) {
  const float* eeg = (const float*)d_in[0];
  const float* fsp = (const float*)d_in[1];
  const float* aw1 = (const float*)d_in[2];
  const float* ab1 = (const float*)d_in[3];
  const float* aw2 = (const float*)d_in[4];
  const float* ab2 = (const float*)d_in[5];
  const float* aw3 = (const float*)d_in[6];
  const float* ab3 = (const float*)d_in[7];
  const float* fw1 = (const float*)d_in[8];
  const float* fb1 = (const float*)d_in[9];
  const float* bng = (const float*)d_in[10];
  const float* bnb = (const float*)d_in[11];
  const float* bnm = (const float*)d_in[12];
  const float* bnv = (const float*)d_in[13];
  const float* fw2 = (const float*)d_in[14];
  const float* fb2 = (const float*)d_in[15];
  float* out = (float*)d_out;
  float* ws = (float*)d_ws;

  hipLaunchKernelGGL(k0_zero, dim3(362), dim3(256), 0, stream, aw2, fw2, fw1, ws);
  hipLaunchKernelGGL(k1_ca, dim3(4, 16, 8), dim3(256), 0, stream, eeg, fsp, ws);
  hipLaunchKernelGGL(k2_conv1, dim3(5, 32, 16), dim3(256), 0, stream, aw1, ab1, ws);
  hipLaunchKernelGGL(k2b_a1s, dim3(512), dim3(256), 0, stream, ws);
  hipLaunchKernelGGL(k3_mfma, dim3(17, 16, 4), dim3(256), 0, stream, ab2, ws);
  hipLaunchKernelGGL(k4a_part, dim3(4, 16, 4), dim3(256), 0, stream, aw3, ws);
  hipLaunchKernelGGL(k4c_sig, dim3(4, 16), dim3(256), 0, stream, ab3, ws, out);
  hipLaunchKernelGGL(k4b_xs, dim3(1024), dim3(256), 0, stream, eeg, fsp, ws);
  hipLaunchKernelGGL(k5_mfma, dim3(17, 16, 2), dim3(256), 0, stream,
                     fb1, bng, bnb, bnm, bnv, ws);
  hipLaunchKernelGGL(k5b_t, dim3(16, 16), dim3(256), 0, stream, ws);
  hipLaunchKernelGGL(k6_mfma, dim3(16, 16, 16), dim3(256), 0, stream, fb2, ws, out);
}

// Round 6
// 178.309 us; speedup vs baseline: 3.5134x; 1.0407x over previous
//
#include <hip/hip_runtime.h>
#include <math.h>

#define Bn 16
#define Cn 64
#define Tn 1024
#define Dn 1024

// ---- workspace layout (float element offsets) ----
#define CA_S   1088
#define CA_OFF 0                                 // [B][1088], end 17408
#define AT_OFF 17408                             // attn [B][1024], end 33792
#define A2_S   1026
#define A2_OFF 599040                            // fp32 a2 [B*64][1026], end 1649664
// XS overlays old A1/A2 float region (dead by the time k4b writes):
#define XS_U   (2*50176)                         // bf16 [4][B*C][1280]
#define HS_S   1040
#define HS_OFF 2671616                           // fp32 [2][B][64][1040], end 4801536
#define HB_OFF 4801536

// ---- ushort offsets ----
#define A1S_U  (2*HS_OFF)                        // bf16 a1 shifted [4][512][1216] (overlays HS; dead before k5)
#define HBT_U  (2*HB_OFF)                        // bf16 hbT [B][1024][64]
#define WFW2_U (HBT_U + 1048576)                 // bf16 fw2 [1024][64]
#define WAW2_U (WFW2_U + 65536)                  // bf16 aw2 [64][32][32]
#define WFW1_U (WAW2_U + 65536)                  // bf16 fw1 [64][128]

typedef __attribute__((ext_vector_type(4))) float f32x4;
typedef __attribute__((ext_vector_type(8))) short bf16x8;
typedef __attribute__((ext_vector_type(4))) unsigned int u32x4;

static __device__ inline unsigned short f2bf(float x) {
  unsigned u = __builtin_bit_cast(unsigned, x);
  return (unsigned short)((u + 0x7fffu + ((u >> 16) & 1u)) >> 16);
}

// KI: blocks 0..63: ca[b][t] = fs/64 * sum_c eeg (overwrite, incl. pads)
//     blocks 64..199: convert aw2 (16384 ids) / fw2 (16384) / fw1 (2048) -> bf16
__global__ void kI_init(const float* __restrict__ eeg, const float* __restrict__ fsp,
                        const float* __restrict__ aw2, const float* __restrict__ fw2,
                        const float* __restrict__ fw1, float* __restrict__ ws) {
  int bx = blockIdx.x, tid = threadIdx.x;
  if (bx < 64) {
    int b = bx >> 2, x = bx & 3;
    int t = x * 256 + tid;
    float s = 0.f;
#pragma unroll 8
    for (int c = 0; c < 64; ++c) s += eeg[(b * 64 + c) * 1024 + t];
    ws[CA_OFF + b * CA_S + 32 + t] = s * fsp[0] * (1.f / 64.f);
    if (x == 0 && tid < 32) ws[CA_OFF + b * CA_S + tid] = 0.f;
    if (x == 3 && tid >= 224) ws[CA_OFF + b * CA_S + 1056 + (tid - 224)] = 0.f;
    return;
  }
  int id = (bx - 64) * 256 + tid;
  if (id < 16384) {                       // aw2: 65536 elems
    int e0 = id * 4;
    float4 f = *(const float4*)&aw2[e0];
    unsigned short* d = (unsigned short*)ws + WAW2_U + e0;
    d[0] = f2bf(f.x); d[1] = f2bf(f.y); d[2] = f2bf(f.z); d[3] = f2bf(f.w);
  } else if (id < 32768) {                // fw2: 65536 elems
    int e0 = (id - 16384) * 4;
    float4 f = *(const float4*)&fw2[e0];
    unsigned short* d = (unsigned short*)ws + WFW2_U + e0;
    d[0] = f2bf(f.x); d[1] = f2bf(f.y); d[2] = f2bf(f.z); d[3] = f2bf(f.w);
  } else if (id < 34816) {                // fw1: 8192 elems
    int e0 = (id - 32768) * 4;
    float4 f = *(const float4*)&fw1[e0];
    unsigned short* d = (unsigned short*)ws + WFW1_U + e0;
    d[0] = f2bf(f.x); d[1] = f2bf(f.y); d[2] = f2bf(f.z); d[3] = f2bf(f.w);
  }
}

// K2s: per (b,o) row: a1 = relu(conv1d(ca, aw1, pad=32)) computed in LDS,
// then write 4 shifted bf16 copies directly. 512 blocks.
__global__ void k2s_conv1(const float* __restrict__ aw1, const float* __restrict__ ab1,
                          float* __restrict__ ws) {
  int row = blockIdx.x;            // b*32 + o
  int b = row >> 5, o = row & 31;
  int tid = threadIdx.x;
  __shared__ unsigned short xl[1232];
  // zero pads only (disjoint from compute writes -> one barrier suffices)
  for (int i = tid; i < 1232; i += 256)
    if (i < 16 || i >= 1041) xl[i] = 0;
  const float* cab = ws + CA_OFF + b * CA_S;
  float bias = ab1[o];
  for (int t = tid; t < 1025; t += 256) {
    float acc = bias;
#pragma unroll 8
    for (int k = 0; k < 64; ++k) acc += aw1[o * 64 + k] * cab[t + k];
    xl[16 + t] = f2bf(fmaxf(acc, 0.f));
  }
  __syncthreads();
  unsigned short* a1s = (unsigned short*)ws + A1S_U;
  for (int q = tid; q < 608; q += 256) {
    int s = q / 152, mm = q % 152;
    int e = mm * 8;
    unsigned a0 = xl[e + s + 0], a1 = xl[e + s + 1], a2 = xl[e + s + 2], a3 = xl[e + s + 3];
    unsigned a4 = xl[e + s + 4], a5 = xl[e + s + 5], a6 = xl[e + s + 6], a7 = xl[e + s + 7];
    uint4 v;
    v.x = a0 | (a1 << 16); v.y = a2 | (a3 << 16); v.z = a4 | (a5 << 16); v.w = a6 | (a7 << 16);
    *(uint4*)&a1s[(s * 512 + row) * 1216 + e] = v;
  }
}

// K3: MFMA conv2. grid(17, B, 4). Writes a2 fp32.
__global__ __launch_bounds__(256) void k3_mfma(const float* __restrict__ ab2,
                                               float* __restrict__ ws) {
  int t0 = blockIdx.x * 64, b = blockIdx.y, oh = blockIdx.z;
  int tid = threadIdx.x, l = tid & 63, w = tid >> 6;
  __shared__ unsigned short wlds[16 * 1032];
  __shared__ unsigned short xlds[32 * 4 * 104];
  const unsigned short* wb = (const unsigned short*)ws + WAW2_U;
  const unsigned short* a1s = (const unsigned short*)ws + A1S_U;
#pragma unroll
  for (int r = 0; r < 8; ++r) {
    int idx = tid + r * 256;
    int o = idx >> 7, j = idx & 127;
    *(uint4*)&wlds[o * 1032 + j * 8] = *(const uint4*)&wb[(oh * 16 + o) * 1024 + j * 8];
  }
#pragma unroll
  for (int r = 0; r < 6; ++r) {
    int idx = tid + r * 256;
    int i = idx / 48, rem = idx % 48, s = rem / 12, mm = rem % 12;
    *(uint4*)&xlds[(i * 4 + s) * 104 + mm * 8] =
        *(const uint4*)&a1s[(s * 512 + b * 32 + i) * 1216 + t0 + mm * 8];
  }
  __syncthreads();
  int m = l & 15, q = l >> 4;
  int A0 = w * 16 + m + q * 8;
  int xoffb = (A0 & 3) * 104 + (A0 & ~3);
  f32x4 acc = (f32x4){0.f, 0.f, 0.f, 0.f};
  for (int i = 0; i < 32; ++i) {
    const uint2* p = (const uint2*)&xlds[i * 416 + xoffb];
    uint2 lo = p[0], hi = p[1];
    u32x4 bb; bb.x = lo.x; bb.y = lo.y; bb.z = hi.x; bb.w = hi.y;
    u32x4 a = *(const u32x4*)&wlds[m * 1032 + i * 32 + q * 8];
    acc = __builtin_amdgcn_mfma_f32_16x16x32_bf16(
        __builtin_bit_cast(bf16x8, a), __builtin_bit_cast(bf16x8, bb), acc, 0, 0, 0);
  }
  int t = t0 + w * 16 + m;
  if (t < 1026) {
#pragma unroll
    for (int r = 0; r < 4; ++r) {
      int o = oh * 16 + q * 4 + r;
      ws[A2_OFF + (b * 64 + o) * A2_S + t] = fmaxf(acc[r] + ab2[o], 0.f);
    }
  }
}

// K4: fused pooled 1x1 conv + sigmoid -> attn + out2. 64 blocks.
__global__ void k4_attn(const float* __restrict__ aw3, const float* __restrict__ ab3,
                        float* __restrict__ ws, float* __restrict__ out) {
  int b = blockIdx.y, t = blockIdx.x * 256 + threadIdx.x;
  int s = t + (t >= 512 ? 1 : 0);
  float acc = 0.f;
#pragma unroll 8
  for (int i = 0; i < 64; ++i) {
    const float* row = ws + A2_OFF + (b * 64 + i) * A2_S;
    acc += aw3[i] * (row[s] + row[s + 1]);
  }
  float a = 1.f / (1.f + expf(-(acc * 0.5f + ab3[0])));
  ws[AT_OFF + b * 1024 + t] = a;
  out[16777216 + b * 1024 + t] = a;
}

// K4b: build 4 shifted bf16 copies of xs_pad = pad64(eeg*fs*attn), row len 1280
__global__ void k4b_xs(const float* __restrict__ eeg, const float* __restrict__ fsp,
                       float* __restrict__ ws) {
  int bc = blockIdx.x;
  int b = bc >> 6;
  int tid = threadIdx.x;
  __shared__ unsigned short xsl[1288];
  float fs = fsp[0];
  for (int i = tid; i < 1288; i += 256) {
    int j = i - 64;
    float v = 0.f;
    if (j >= 0 && j < 1024) v = eeg[bc * 1024 + j] * fs * ws[AT_OFF + b * 1024 + j];
    xsl[i] = f2bf(v);
  }
  __syncthreads();
  unsigned short* xsg = (unsigned short*)ws + XS_U;
  for (int q = tid; q < 640; q += 256) {
    int s = q / 160, m = q % 160, e = m * 8;
    uint4 v;
    unsigned a0 = xsl[e + s + 0], a1 = xsl[e + s + 1], a2 = xsl[e + s + 2], a3 = xsl[e + s + 3];
    unsigned a4 = xsl[e + s + 4], a5 = xsl[e + s + 5], a6 = xsl[e + s + 6], a7 = xsl[e + s + 7];
    v.x = a0 | (a1 << 16); v.y = a2 | (a3 << 16); v.z = a4 | (a5 << 16); v.w = a6 | (a7 << 16);
    *(uint4*)&xsg[(s * 1024 + bc) * 1280 + e] = v;
  }
}

// K5: MFMA stage-B conv. Weight frags direct from global (L2-hot 16KB);
// LDS = xlds only (51.2KB) -> 3 blocks/CU, 544 blocks ~ one round.
__global__ __launch_bounds__(256, 3) void k5_mfma(
    const float* __restrict__ fb1,
    const float* __restrict__ bng, const float* __restrict__ bnb,
    const float* __restrict__ bnm, const float* __restrict__ bnv,
    float* __restrict__ ws) {
  int t0 = blockIdx.x * 64, b = blockIdx.y, g2 = blockIdx.z;
  int tid = threadIdx.x, l = tid & 63, w = tid >> 6;
  __shared__ unsigned short xlds[32 * 4 * 200];
  const unsigned short* wbf = (const unsigned short*)ws + WFW1_U;
  const unsigned short* xsg = (const unsigned short*)ws + XS_U;
#pragma unroll
  for (int r = 0; r < 12; ++r) {
    int q = tid + r * 256;
    int ch = q / 96, rem = q % 96, s = rem / 24, m = rem % 24;
    int c = g2 * 32 + ch;
    uint4 v = *(const uint4*)&xsg[((s * 1024) + b * 64 + c) * 1280 + t0 + m * 8];
    *(uint4*)&xlds[(ch * 4 + s) * 200 + m * 8] = v;
  }
  u32x4 wf[4][4];
#pragma unroll
  for (int mt = 0; mt < 4; ++mt)
#pragma unroll
    for (int ks = 0; ks < 4; ++ks)
      wf[mt][ks] = *(const u32x4*)&wbf[(mt * 16 + (l & 15)) * 128 + ks * 32 + (l >> 4) * 8];
  int row0 = (l >> 4) * 4;
  float scv[4][4], shv[4][4];
#pragma unroll
  for (int mt = 0; mt < 4; ++mt)
#pragma unroll
    for (int r = 0; r < 4; ++r) {
      int o = mt * 16 + row0 + r;
      float s = bng[o] * rsqrtf(bnv[o] + 1e-5f);
      scv[mt][r] = s;
      shv[mt][r] = (fb1[o] - bnm[o]) * s + bnb[o];
    }
  int xoff[4];
#pragma unroll
  for (int ks = 0; ks < 4; ++ks) {
    int A0 = (l & 15) + ks * 32 + (l >> 4) * 8;
    int s = A0 & 3, e = A0 & ~3;
    xoff[ks] = s * 200 + w * 16 + e;
  }
  __syncthreads();
  f32x4 acc[4];
#pragma unroll
  for (int mt = 0; mt < 4; ++mt) acc[mt] = (f32x4){0.f, 0.f, 0.f, 0.f};
  for (int ch = 0; ch < 32; ++ch) {
    u32x4 bf[4];
#pragma unroll
    for (int ks = 0; ks < 4; ++ks) {
      const uint2* p = (const uint2*)&xlds[ch * 800 + xoff[ks]];
      uint2 lo = p[0], hi = p[1];
      u32x4 bb; bb.x = lo.x; bb.y = lo.y; bb.z = hi.x; bb.w = hi.y;
      bf[ks] = bb;
    }
#pragma unroll
    for (int mt = 0; mt < 4; ++mt) {
      f32x4 c = (f32x4){0.f, 0.f, 0.f, 0.f};
#pragma unroll
      for (int ks = 0; ks < 4; ++ks)
        c = __builtin_amdgcn_mfma_f32_16x16x32_bf16(
            __builtin_bit_cast(bf16x8, wf[mt][ks]),
            __builtin_bit_cast(bf16x8, bf[ks]), c, 0, 0, 0);
#pragma unroll
      for (int r = 0; r < 4; ++r)
        acc[mt][r] += fmaxf(c[r] * scv[mt][r] + shv[mt][r], 0.f);
    }
  }
  int t = t0 + w * 16 + (l & 15);
  if (t < 1025) {
#pragma unroll
    for (int mt = 0; mt < 4; ++mt)
#pragma unroll
      for (int r = 0; r < 4; ++r)
        ws[HS_OFF + (((g2 * 16 + b) * 64) + mt * 16 + row0 + r) * HS_S + t] = acc[mt][r];
  }
}

// K5b: pool + channel-mean + transpose -> hbT[b][t][k] bf16
__global__ void k5b_t(float* __restrict__ ws) {
  int tt = blockIdx.x, b = blockIdx.y;
  int tid = threadIdx.x;
  __shared__ unsigned short tr[64 * 80];
  int k = tid >> 2, q = tid & 3;
  const float* r0 = ws + HS_OFF + ((0 + b) * 64 + k) * HS_S + tt * 64;
  const float* r1 = ws + HS_OFF + ((16 + b) * 64 + k) * HS_S + tt * 64;
#pragma unroll
  for (int j = 0; j < 16; ++j) {
    int tl = q * 16 + j;
    float v = r0[tl] + r0[tl + 1] + r1[tl] + r1[tl + 1];
    tr[tl * 80 + k] = f2bf(v * (1.f / 128.f));
  }
  __syncthreads();
  unsigned short* hbT = (unsigned short*)ws + HBT_U;
#pragma unroll
  for (int r = 0; r < 2; ++r) {
    int idx = tid + r * 256;
    int tl = idx >> 3, j = idx & 7;
    uint4 v = *(uint4*)&tr[tl * 80 + j * 8];
    *(uint4*)&hbT[(b * 1024 + tt * 64 + tl) * 64 + j * 8] = v;
  }
}

// K6: MFMA out-GEMM: out[b][d][t] = sum_k fw2[d][k]*hb[k][t] + fb2[d]
__global__ __launch_bounds__(256) void k6_mfma(const float* __restrict__ fb2,
                                               float* __restrict__ ws,
                                               float* __restrict__ out) {
  int tt = blockIdx.x, dt = blockIdx.y, b = blockIdx.z;
  int tid = threadIdx.x, l = tid & 63, w = tid >> 6;
  int wd = w >> 1, wt = w & 1;
  __shared__ unsigned short wA[64 * 80], xB[64 * 80];
  const unsigned short* w2 = (const unsigned short*)ws + WFW2_U;
  const unsigned short* hbT = (const unsigned short*)ws + HBT_U;
#pragma unroll
  for (int r = 0; r < 2; ++r) {
    int idx = tid + r * 256;
    int row = idx >> 3, j = idx & 7;
    *(uint4*)&wA[row * 80 + j * 8] = *(const uint4*)&w2[(dt * 64 + row) * 64 + j * 8];
    *(uint4*)&xB[row * 80 + j * 8] = *(const uint4*)&hbT[(b * 1024 + tt * 64 + row) * 64 + j * 8];
  }
  __syncthreads();
  int m = l & 15, q = l >> 4;
  f32x4 acc[2][2];
#pragma unroll
  for (int mt = 0; mt < 2; ++mt)
#pragma unroll
    for (int nt = 0; nt < 2; ++nt) acc[mt][nt] = (f32x4){0.f, 0.f, 0.f, 0.f};
#pragma unroll
  for (int ks = 0; ks < 2; ++ks) {
    u32x4 a[2], bb[2];
#pragma unroll
    for (int mt = 0; mt < 2; ++mt)
      a[mt] = *(const u32x4*)&wA[(wd * 32 + mt * 16 + m) * 80 + ks * 32 + q * 8];
#pragma unroll
    for (int nt = 0; nt < 2; ++nt)
      bb[nt] = *(const u32x4*)&xB[(wt * 32 + nt * 16 + m) * 80 + ks * 32 + q * 8];
#pragma unroll
    for (int mt = 0; mt < 2; ++mt)
#pragma unroll
      for (int nt = 0; nt < 2; ++nt)
        acc[mt][nt] = __builtin_amdgcn_mfma_f32_16x16x32_bf16(
            __builtin_bit_cast(bf16x8, a[mt]), __builtin_bit_cast(bf16x8, bb[nt]),
            acc[mt][nt], 0, 0, 0);
  }
#pragma unroll
  for (int mt = 0; mt < 2; ++mt) {
#pragma unroll
    for (int r = 0; r < 4; ++r) {
      int d = dt * 64 + wd * 32 + mt * 16 + q * 4 + r;
      float bias = fb2[d];
#pragma unroll
      for (int nt = 0; nt < 2; ++nt) {
        int t = tt * 64 + wt * 32 + nt * 16 + m;
        out[(b * 1024 + d) * 1024 + t] = acc[mt][nt][r] + bias;
      }
    }
  }
}

extern "C" void kernel_launch(void* const* d_in, const int* in_sizes, int n_in,
                              void* d_out, int out_size, void* d_ws, size_t ws_size,
                              hipStream_t stream) {
  const float* eeg = (const float*)d_in[0];
  const float* fsp = (const float*)d_in[1];
  const float* aw1 = (const float*)d_in[2];
  const float* ab1 = (const float*)d_in[3];
  const float* aw2 = (const float*)d_in[4];
  const float* ab2 = (const float*)d_in[5];
  const float* aw3 = (const float*)d_in[6];
  const float* ab3 = (const float*)d_in[7];
  const float* fw1 = (const float*)d_in[8];
  const float* fb1 = (const float*)d_in[9];
  const float* bng = (const float*)d_in[10];
  const float* bnb = (const float*)d_in[11];
  const float* bnm = (const float*)d_in[12];
  const float* bnv = (const float*)d_in[13];
  const float* fw2 = (const float*)d_in[14];
  const float* fb2 = (const float*)d_in[15];
  float* out = (float*)d_out;
  float* ws = (float*)d_ws;

  hipLaunchKernelGGL(kI_init, dim3(200), dim3(256), 0, stream, eeg, fsp, aw2, fw2, fw1, ws);
  hipLaunchKernelGGL(k2s_conv1, dim3(512), dim3(256), 0, stream, aw1, ab1, ws);
  hipLaunchKernelGGL(k3_mfma, dim3(17, 16, 4), dim3(256), 0, stream, ab2, ws);
  hipLaunchKernelGGL(k4_attn, dim3(4, 16), dim3(256), 0, stream, aw3, ab3, ws, out);
  hipLaunchKernelGGL(k4b_xs, dim3(1024), dim3(256), 0, stream, eeg, fsp, ws);
  hipLaunchKernelGGL(k5_mfma, dim3(17, 16, 2), dim3(256), 0, stream,
                     fb1, bng, bnb, bnm, bnv, ws);
  hipLaunchKernelGGL(k5b_t, dim3(16, 16), dim3(256), 0, stream, ws);
  hipLaunchKernelGGL(k6_mfma, dim3(16, 16, 16), dim3(256), 0, stream, fb2, ws, out);
}